// Round 10
// baseline (203.833 us; speedup 1.0000x reference)
//
#include <hip/hip_runtime.h>
#include <hip/hip_bf16.h>
#include <cstdint>
#include <cstddef>

#define DIN 512
#define DH  96
#define DOUT 40

typedef __attribute__((ext_vector_type(8))) short s8v;
typedef __attribute__((ext_vector_type(4))) float f4v;

__device__ __forceinline__ ushort f2bf(float f) {
    uint u = __float_as_uint(f);
    u += 0x7fffu + ((u >> 16) & 1u);   // RNE
    return (ushort)(u >> 16);
}
__device__ __forceinline__ uint f2bf2(float lo, float hi) {
    __hip_bfloat162 h = __float22bfloat162_rn(make_float2(lo, hi));  // v_cvt_pk_bf16_f32
    return *(uint*)&h;
}
__device__ __forceinline__ float bflo(uint u) { return __uint_as_float(u << 16); }
__device__ __forceinline__ float bfhi(uint u) { return __uint_as_float(u & 0xffff0000u); }

// ---------- prep: zero cnt + W1T bf16 [96][512] + W2T bf16 [48][96] ----------
__global__ __launch_bounds__(256) void k_prep(
    const float* __restrict__ W1, const float* __restrict__ W2,
    int* __restrict__ cnt, ushort* __restrict__ W1T, ushort* __restrict__ W2T, int N)
{
    int i = blockIdx.x * 256 + threadIdx.x;
    if (i < N) cnt[i] = 0;
    if (i < DIN * DH) {
        int k = i / DH, n = i % DH;
        W1T[(size_t)n * DIN + k] = f2bf(W1[i]);
    }
    if (i < 48 * DH) {
        int n = i / DH, k = i % DH;
        W2T[i] = (n < DOUT) ? f2bf(W2[(size_t)k * DOUT + n]) : (ushort)0;
    }
}

// ---------- hist + per-edge slot ----------
__global__ __launch_bounds__(256) void k_hist(
    const int* __restrict__ dst, int* __restrict__ cnt, int* __restrict__ pos, int E)
{
    int e = blockIdx.x * 256 + threadIdx.x;
    if (e < E) pos[e] = atomicAdd(&cnt[dst[e]], 1);
}

// ---------- row_ptr + dinv in ONE kernel (block-redundant prefix) ----------
__global__ __launch_bounds__(256) void k_rowptr_all(
    const int* __restrict__ cnt, int* __restrict__ row_ptr,
    float* __restrict__ dinv, int N)
{
    __shared__ int p[256];
    __shared__ int wred[4];
    const int tid = threadIdx.x, b = blockIdx.x;

    int pre = 0;
    const int limit = b * 256;
    for (int j = tid; j < limit; j += 256) pre += cnt[j];
    #pragma unroll
    for (int off = 32; off >= 1; off >>= 1) pre += __shfl_down(pre, off, 64);
    if ((tid & 63) == 0) wred[tid >> 6] = pre;
    __syncthreads();
    const int base0 = wred[0] + wred[1] + wred[2] + wred[3];

    int i = b * 256 + tid;
    int c = (i < N) ? cnt[i] : 0;
    p[tid] = c;
    __syncthreads();
    #pragma unroll
    for (int off = 1; off < 256; off <<= 1) {
        int t = (tid >= off) ? p[tid - off] : 0;
        __syncthreads();
        p[tid] += t;
        __syncthreads();
    }
    int excl = p[tid] - c;
    if (i < N) {
        int base = base0 + excl;
        row_ptr[i] = base;
        dinv[i] = rsqrtf(1.0f + (float)c);
        if (i == N - 1) row_ptr[N] = base + c;
    }
}

// ---------- CSR fill (atomic-free) ----------
__global__ __launch_bounds__(256) void k_fill(
    const int* __restrict__ src, const int* __restrict__ dst,
    const int* __restrict__ row_ptr, const int* __restrict__ pos,
    int* __restrict__ adj, int E)
{
    int e = blockIdx.x * 256 + threadIdx.x;
    if (e >= E) return;
    adj[row_ptr[dst[e]] + pos[e]] = src[e];
}

// ---------- GEMM1 (MFMA bf16): 256 thr, 64-row tile, BK=32 dbuf, 20KB LDS ----------
// grid = ceil(N/64) = 782 blocks -> ~3 blocks/CU resident
#define SWZ(r) (((r >> 1) & 3) << 3)
__global__ __launch_bounds__(256) void k_gemm1(
    const float* __restrict__ x, const ushort* __restrict__ W1T,
    const float* __restrict__ dinv, ushort* __restrict__ hs1, int N)
{
    __shared__ __align__(16) ushort lds[10240];   // A: 2*2048 @0, B: 2*3072 @4096
    const int tid = threadIdx.x;
    const int row0 = blockIdx.x * 64;
    const int lane = tid & 63, w = tid >> 6;      // 4 waves: 2 row x 2 col groups
    const int rb = (w >> 1) * 32, cb = (w & 1) * 48;
    const int lm = lane & 15, lq = lane >> 4;

    int aof[2], bof[3];
    #pragma unroll
    for (int i = 0; i < 2; ++i) {
        int r = rb + i * 16 + lm;
        aof[i] = r * 32 + ((lq * 8) ^ SWZ(r));
    }
    #pragma unroll
    for (int j = 0; j < 3; ++j) {
        int n = cb + j * 16 + lm;
        bof[j] = 4096 + n * 32 + ((lq * 8) ^ SWZ(n));
    }

    f4v acc[2][3];
    #pragma unroll
    for (int i = 0; i < 2; ++i)
        #pragma unroll
        for (int j = 0; j < 3; ++j) acc[i][j] = (f4v)0.f;

    const int sr = tid >> 2;            // staging row 0..63
    const int c0 = (tid & 3) * 8;       // 8 cols per thread

    auto stage = [&](int kt, int buf) {
        int k0 = kt * 32;
        int gr = row0 + sr;
        ushort* A = lds + buf * 2048;
        float4 v0 = make_float4(0.f, 0.f, 0.f, 0.f), v1 = v0;
        if (gr < N) {
            const float* pp = &x[(size_t)gr * DIN + k0 + c0];
            v0 = *(const float4*)pp;
            v1 = *(const float4*)(pp + 4);
        }
        uint4 wv;
        wv.x = f2bf2(v0.x, v0.y);
        wv.y = f2bf2(v0.z, v0.w);
        wv.z = f2bf2(v1.x, v1.y);
        wv.w = f2bf2(v1.z, v1.w);
        *(uint4*)&A[sr * 32 + (c0 ^ SWZ(sr))] = wv;
        ushort* B = lds + 4096 + buf * 3072;
        #pragma unroll
        for (int f = tid; f < 384; f += 256) {
            int n = f >> 2, cc = (f & 3) * 8;
            uint4 bv = *(const uint4*)&W1T[(size_t)n * DIN + k0 + cc];
            *(uint4*)&B[n * 32 + (cc ^ SWZ(n))] = bv;
        }
    };

    stage(0, 0);
    for (int kt = 0; kt < 16; ++kt) {
        __syncthreads();
        if (kt < 15) stage(kt + 1, (kt + 1) & 1);
        const int ab = (kt & 1) * 2048;
        const int bb = (kt & 1) * 3072;
        s8v b0 = *(s8v*)&lds[bof[0] + bb];
        s8v b1 = *(s8v*)&lds[bof[1] + bb];
        s8v b2 = *(s8v*)&lds[bof[2] + bb];
        #pragma unroll
        for (int i = 0; i < 2; ++i) {
            s8v a = *(s8v*)&lds[aof[i] + ab];
            acc[i][0] = __builtin_amdgcn_mfma_f32_16x16x32_bf16(a, b0, acc[i][0], 0, 0, 0);
            acc[i][1] = __builtin_amdgcn_mfma_f32_16x16x32_bf16(a, b1, acc[i][1], 0, 0, 0);
            acc[i][2] = __builtin_amdgcn_mfma_f32_16x16x32_bf16(a, b2, acc[i][2], 0, 0, 0);
        }
    }

    #pragma unroll
    for (int i = 0; i < 2; ++i) {
        int gr0 = row0 + rb + i * 16 + lq * 4;
        #pragma unroll
        for (int q = 0; q < 4; ++q) {
            int gr = gr0 + q;
            if (gr < N) {
                float di = dinv[gr];
                #pragma unroll
                for (int j = 0; j < 3; ++j)
                    hs1[(size_t)gr * DH + cb + j * 16 + lm] = f2bf(acc[i][j][q] * di);
            }
        }
    }
}

// ---------- agg1: wave per node, 48 lanes x uint, 8-deep (R8 form) ----------
__global__ __launch_bounds__(256) void k_agg1(
    const int* __restrict__ row_ptr, const int* __restrict__ adj,
    const float* __restrict__ dinv, const ushort* __restrict__ hs1,
    const float* __restrict__ b1, ushort* __restrict__ h1, int N)
{
    int t = blockIdx.x * 256 + threadIdx.x;
    int node = t >> 6, lane = t & 63;
    if (node >= N) return;
    int c = lane << 1;
    const bool act = (c < DH);

    float a0 = 0.f, a1 = 0.f;
    if (act) {
        uint u = *(const uint*)&hs1[(size_t)node * DH + c];   // self-loop
        a0 = bflo(u); a1 = bfhi(u);
    }
    int e = row_ptr[node], e1 = row_ptr[node + 1];
    for (; e + 7 < e1; e += 8) {
        int s0 = adj[e],     s1 = adj[e + 1], s2 = adj[e + 2], s3 = adj[e + 3];
        int s4 = adj[e + 4], s5 = adj[e + 5], s6 = adj[e + 6], s7 = adj[e + 7];
        if (act) {
            uint u0 = *(const uint*)&hs1[(size_t)s0 * DH + c];
            uint u1 = *(const uint*)&hs1[(size_t)s1 * DH + c];
            uint u2 = *(const uint*)&hs1[(size_t)s2 * DH + c];
            uint u3 = *(const uint*)&hs1[(size_t)s3 * DH + c];
            uint u4 = *(const uint*)&hs1[(size_t)s4 * DH + c];
            uint u5 = *(const uint*)&hs1[(size_t)s5 * DH + c];
            uint u6 = *(const uint*)&hs1[(size_t)s6 * DH + c];
            uint u7 = *(const uint*)&hs1[(size_t)s7 * DH + c];
            a0 += bflo(u0); a1 += bfhi(u0);
            a0 += bflo(u1); a1 += bfhi(u1);
            a0 += bflo(u2); a1 += bfhi(u2);
            a0 += bflo(u3); a1 += bfhi(u3);
            a0 += bflo(u4); a1 += bfhi(u4);
            a0 += bflo(u5); a1 += bfhi(u5);
            a0 += bflo(u6); a1 += bfhi(u6);
            a0 += bflo(u7); a1 += bfhi(u7);
        }
    }
    for (; e < e1; ++e) {
        int s = adj[e];
        if (act) {
            uint u = *(const uint*)&hs1[(size_t)s * DH + c];
            a0 += bflo(u); a1 += bfhi(u);
        }
    }
    if (act) {
        float di = dinv[node];
        float r0 = fmaxf(fmaf(a0, di, b1[c]), 0.f);
        float r1 = fmaxf(fmaf(a1, di, b1[c + 1]), 0.f);
        *(uint*)&h1[(size_t)node * DH + c] = f2bf2(r0, r1);
    }
}

// ---------- GEMM2 (MFMA bf16): hs2b = bf16((h1 @ W2) * dinv), row stride 64 ----------
__global__ __launch_bounds__(256) void k_gemm2(
    const ushort* __restrict__ h1, const ushort* __restrict__ W2T,
    const float* __restrict__ dinv, ushort* __restrict__ hs2b, int N)
{
    __shared__ __align__(16) ushort lds[16384 + 48 * 128];
    const int tid = threadIdx.x;
    const int row0 = blockIdx.x * 128;

    for (int f = tid; f < 576; f += 256) {
        int r = f / 12, c = (f % 12) * 8;
        uint4 v = *(const uint4*)&W2T[r * DH + c];
        *(uint4*)&lds[16384 + r * 128 + (c ^ ((r & 7) << 3))] = v;
    }
    {
        int r = tid >> 1, half = tid & 1;
        int gr = row0 + r;
        #pragma unroll
        for (int i = 0; i < 6; ++i) {
            int c = half * 48 + i * 8;
            uint4 v = make_uint4(0, 0, 0, 0);
            if (gr < N) v = *(const uint4*)&h1[(size_t)gr * DH + c];
            *(uint4*)&lds[r * 128 + (c ^ ((r & 7) << 3))] = v;
        }
    }
    __syncthreads();

    const int lane = tid & 63, w = tid >> 6;
    const int rb = w * 32, lm = lane & 15, lq = lane >> 4;
    f4v acc[2][3];
    #pragma unroll
    for (int i = 0; i < 2; ++i)
        #pragma unroll
        for (int j = 0; j < 3; ++j) acc[i][j] = (f4v)0.f;

    #pragma unroll
    for (int ks = 0; ks < 3; ++ks) {
        int kk = ks * 32 + lq * 8;
        s8v b[3];
        #pragma unroll
        for (int j = 0; j < 3; ++j) {
            int n = j * 16 + lm;
            b[j] = *(s8v*)&lds[16384 + n * 128 + (kk ^ ((n & 7) << 3))];
        }
        #pragma unroll
        for (int i = 0; i < 2; ++i) {
            int r = rb + i * 16 + lm;
            s8v a = *(s8v*)&lds[r * 128 + (kk ^ ((r & 7) << 3))];
            #pragma unroll
            for (int j = 0; j < 3; ++j)
                acc[i][j] = __builtin_amdgcn_mfma_f32_16x16x32_bf16(a, b[j], acc[i][j], 0, 0, 0);
        }
    }

    #pragma unroll
    for (int i = 0; i < 2; ++i) {
        int gr0 = row0 + rb + i * 16 + lq * 4;
        #pragma unroll
        for (int q = 0; q < 4; ++q) {
            int gr = gr0 + q;
            if (gr < N) {
                float di = dinv[gr];
                #pragma unroll
                for (int j = 0; j < 3; ++j) {
                    int col = j * 16 + lm;
                    if (col < DOUT)
                        hs2b[(size_t)gr * 64 + col] = f2bf(acc[i][j][q] * di);
                }
            }
        }
    }
}

// ---------- agg2 + bias + log_softmax: wave per node, 20 lanes x uint (R8 form) ----------
__global__ __launch_bounds__(256) void k_agg2sm(
    const int* __restrict__ row_ptr, const int* __restrict__ adj,
    const float* __restrict__ dinv, const ushort* __restrict__ hs2b,
    const float* __restrict__ b2, float* __restrict__ out,
    float* __restrict__ lsm, int N)
{
    int t = blockIdx.x * 256 + threadIdx.x;
    int node = t >> 6, lane = t & 63;
    if (node >= N) return;
    int c = lane << 1;
    const bool act = (c < DOUT);   // lanes 0..19

    float a0 = 0.f, a1 = 0.f;
    if (act) {
        uint u = *(const uint*)&hs2b[(size_t)node * 64 + c];   // self-loop
        a0 = bflo(u); a1 = bfhi(u);
    }
    int e = row_ptr[node], e1 = row_ptr[node + 1];
    for (; e + 7 < e1; e += 8) {
        int s0 = adj[e],     s1 = adj[e + 1], s2 = adj[e + 2], s3 = adj[e + 3];
        int s4 = adj[e + 4], s5 = adj[e + 5], s6 = adj[e + 6], s7 = adj[e + 7];
        if (act) {
            uint u0 = *(const uint*)&hs2b[(size_t)s0 * 64 + c];
            uint u1 = *(const uint*)&hs2b[(size_t)s1 * 64 + c];
            uint u2 = *(const uint*)&hs2b[(size_t)s2 * 64 + c];
            uint u3 = *(const uint*)&hs2b[(size_t)s3 * 64 + c];
            uint u4 = *(const uint*)&hs2b[(size_t)s4 * 64 + c];
            uint u5 = *(const uint*)&hs2b[(size_t)s5 * 64 + c];
            uint u6 = *(const uint*)&hs2b[(size_t)s6 * 64 + c];
            uint u7 = *(const uint*)&hs2b[(size_t)s7 * 64 + c];
            a0 += bflo(u0); a1 += bfhi(u0);
            a0 += bflo(u1); a1 += bfhi(u1);
            a0 += bflo(u2); a1 += bfhi(u2);
            a0 += bflo(u3); a1 += bfhi(u3);
            a0 += bflo(u4); a1 += bfhi(u4);
            a0 += bflo(u5); a1 += bfhi(u5);
            a0 += bflo(u6); a1 += bfhi(u6);
            a0 += bflo(u7); a1 += bfhi(u7);
        }
    }
    for (; e < e1; ++e) {
        int s = adj[e];
        if (act) {
            uint u = *(const uint*)&hs2b[(size_t)s * 64 + c];
            a0 += bflo(u); a1 += bfhi(u);
        }
    }

    float di = act ? dinv[node] : 0.f;
    float v0 = act ? fmaf(a0, di, b2[c]) : -1e30f;
    float v1 = act ? fmaf(a1, di, b2[c + 1]) : -1e30f;
    float m = fmaxf(v0, v1);
    #pragma unroll
    for (int off = 32; off >= 1; off >>= 1) m = fmaxf(m, __shfl_xor(m, off));
    float ex = act ? (__expf(v0 - m) + __expf(v1 - m)) : 0.f;
    float s = ex;
    #pragma unroll
    for (int off = 32; off >= 1; off >>= 1) s += __shfl_xor(s, off);
    float lse = m + __logf(s);
    if (act) {
        *(float2*)&out[(size_t)node * DOUT + c] = make_float2(v0, v1);
        *(float2*)&lsm[(size_t)node * DOUT + c] = make_float2(v0 - lse, v1 - lse);
    }
}

extern "C" void kernel_launch(void* const* d_in, const int* in_sizes, int n_in,
                              void* d_out, int out_size, void* d_ws, size_t ws_size,
                              hipStream_t stream) {
    const float* x  = (const float*)d_in[0];
    const int*   ei = (const int*)d_in[1];
    const float* W1 = (const float*)d_in[2];
    const float* b1 = (const float*)d_in[3];
    const float* W2 = (const float*)d_in[4];
    const float* b2 = (const float*)d_in[5];

    const int N = in_sizes[0] / DIN;
    const int E = in_sizes[1] / 2;
    const int* srcp = ei;
    const int* dstp = ei + E;
    const int SB = (N + 255) / 256;

    ushort* hs1  = (ushort*)d_ws;                   // N*96 bf16
    ushort* h1   = hs1 + (size_t)N * DH;            // N*96 bf16
    ushort* hs2b = h1 + (size_t)N * DH;             // N*64 bf16 (40 used, 128B rows)
    float* dinv  = (float*)(hs2b + (size_t)N * 64); // N
    ushort* W1T  = (ushort*)(dinv + N);             // 96*512 bf16
    ushort* W2T  = W1T + (size_t)DH * DIN;          // 48*96 bf16
    int* cnt     = (int*)(W2T + 48 * DH);           // N
    int* row_ptr = cnt + N;                         // N+1
    int* adj     = row_ptr + N + 1;                 // E
    int* pos     = adj + E;                         // E

    float* out = (float*)d_out;                     // logits [N*40]
    float* lsm = out + (size_t)N * DOUT;            // log_softmax [N*40]

    const int gE = (E + 255) / 256;

    k_prep<<<SB, 256, 0, stream>>>(W1, W2, cnt, W1T, W2T, N);
    k_hist<<<gE, 256, 0, stream>>>(dstp, cnt, pos, E);
    k_rowptr_all<<<SB, 256, 0, stream>>>(cnt, row_ptr, dinv, N);
    k_fill<<<gE, 256, 0, stream>>>(srcp, dstp, row_ptr, pos, adj, E);

    k_gemm1<<<(N + 63) / 64, 256, 0, stream>>>(x, W1T, dinv, hs1, N);
    k_agg1<<<(int)(((size_t)N * 64 + 255) / 256), 256, 0, stream>>>(row_ptr, adj, dinv, hs1, b1, h1, N);

    k_gemm2<<<(N + 127) / 128, 256, 0, stream>>>(h1, W2T, dinv, hs2b, N);
    k_agg2sm<<<(int)(((size_t)N * 64 + 255) / 256), 256, 0, stream>>>(row_ptr, adj, dinv, hs2b, b2, out, lsm, N);
}

// Round 11
// 199.976 us; speedup vs baseline: 1.0193x; 1.0193x over previous
//
#include <hip/hip_runtime.h>
#include <hip/hip_bf16.h>
#include <cstdint>
#include <cstddef>

#define DIN 512
#define DH  96
#define DOUT 40

typedef __attribute__((ext_vector_type(8))) short s8v;
typedef __attribute__((ext_vector_type(4))) float f4v;

__device__ __forceinline__ ushort f2bf(float f) {
    uint u = __float_as_uint(f);
    u += 0x7fffu + ((u >> 16) & 1u);   // RNE
    return (ushort)(u >> 16);
}
__device__ __forceinline__ uint f2bf2(float lo, float hi) {
    __hip_bfloat162 h = __float22bfloat162_rn(make_float2(lo, hi));  // v_cvt_pk_bf16_f32
    return *(uint*)&h;
}
__device__ __forceinline__ float bflo(uint u) { return __uint_as_float(u << 16); }
__device__ __forceinline__ float bfhi(uint u) { return __uint_as_float(u & 0xffff0000u); }

// ---------- prep: zero cnt + W1T bf16 [96][512] + W2T bf16 [48][96] ----------
__global__ __launch_bounds__(256) void k_prep(
    const float* __restrict__ W1, const float* __restrict__ W2,
    int* __restrict__ cnt, ushort* __restrict__ W1T, ushort* __restrict__ W2T, int N)
{
    int i = blockIdx.x * 256 + threadIdx.x;
    if (i < N) cnt[i] = 0;
    if (i < DIN * DH) {
        int k = i / DH, n = i % DH;
        W1T[(size_t)n * DIN + k] = f2bf(W1[i]);
    }
    if (i < 48 * DH) {
        int n = i / DH, k = i % DH;
        W2T[i] = (n < DOUT) ? f2bf(W2[(size_t)k * DOUT + n]) : (ushort)0;
    }
}

// ---------- hist + per-edge slot ----------
__global__ __launch_bounds__(256) void k_hist(
    const int* __restrict__ dst, int* __restrict__ cnt, int* __restrict__ pos, int E)
{
    int e = blockIdx.x * 256 + threadIdx.x;
    if (e < E) pos[e] = atomicAdd(&cnt[dst[e]], 1);
}

// ---------- row_ptr + dinv in ONE kernel (block-redundant prefix) ----------
__global__ __launch_bounds__(256) void k_rowptr_all(
    const int* __restrict__ cnt, int* __restrict__ row_ptr,
    float* __restrict__ dinv, int N)
{
    __shared__ int p[256];
    __shared__ int wred[4];
    const int tid = threadIdx.x, b = blockIdx.x;

    int pre = 0;
    const int limit = b * 256;
    for (int j = tid; j < limit; j += 256) pre += cnt[j];
    #pragma unroll
    for (int off = 32; off >= 1; off >>= 1) pre += __shfl_down(pre, off, 64);
    if ((tid & 63) == 0) wred[tid >> 6] = pre;
    __syncthreads();
    const int base0 = wred[0] + wred[1] + wred[2] + wred[3];

    int i = b * 256 + tid;
    int c = (i < N) ? cnt[i] : 0;
    p[tid] = c;
    __syncthreads();
    #pragma unroll
    for (int off = 1; off < 256; off <<= 1) {
        int t = (tid >= off) ? p[tid - off] : 0;
        __syncthreads();
        p[tid] += t;
        __syncthreads();
    }
    int excl = p[tid] - c;
    if (i < N) {
        int base = base0 + excl;
        row_ptr[i] = base;
        dinv[i] = rsqrtf(1.0f + (float)c);
        if (i == N - 1) row_ptr[N] = base + c;
    }
}

// ---------- CSR fill (atomic-free) ----------
__global__ __launch_bounds__(256) void k_fill(
    const int* __restrict__ src, const int* __restrict__ dst,
    const int* __restrict__ row_ptr, const int* __restrict__ pos,
    int* __restrict__ adj, int E)
{
    int e = blockIdx.x * 256 + threadIdx.x;
    if (e >= E) return;
    adj[row_ptr[dst[e]] + pos[e]] = src[e];
}

// ---------- GEMM1 (MFMA bf16): 128-row tile, BK=32, async reg-prefetch staging ----------
#define SWZ(r) (((r >> 1) & 3) << 3)
__global__ __launch_bounds__(256) void k_gemm1(
    const float* __restrict__ x, const ushort* __restrict__ W1T,
    const float* __restrict__ dinv, ushort* __restrict__ hs1, int N)
{
    __shared__ __align__(16) ushort lds[14336];   // A: 2*4096 @0, B: 2*3072 @8192
    const int tid = threadIdx.x;
    const int row0 = blockIdx.x * 128;
    const int lane = tid & 63, w = tid >> 6;
    const int rb = (w >> 1) * 64, cb = (w & 1) * 48;
    const int lm = lane & 15, lq = lane >> 4;

    int aof[4], bof[3];
    #pragma unroll
    for (int i = 0; i < 4; ++i) {
        int r = rb + i * 16 + lm;
        aof[i] = r * 32 + ((lq * 8) ^ SWZ(r));
    }
    #pragma unroll
    for (int j = 0; j < 3; ++j) {
        int n = cb + j * 16 + lm;
        bof[j] = 8192 + n * 32 + ((lq * 8) ^ SWZ(n));
    }

    f4v acc[4][3];
    #pragma unroll
    for (int i = 0; i < 4; ++i)
        #pragma unroll
        for (int j = 0; j < 3; ++j) acc[i][j] = (f4v)0.f;

    // staging assignments
    const int sr = tid >> 1, c0 = (tid & 1) * 16;           // A: row, col base (16 cols)
    const int bn0 = tid >> 2, bc0 = (tid & 3) * 8;          // B row 0..63
    const int bn1 = (tid + 256) >> 2, bc1 = (tid & 3) * 8;  // B row 64..95 (tid<128)
    const bool hasB1 = tid < 128;
    const int gr = row0 + sr;
    const bool grok = gr < N;

    float4 ra[2][2];
    uint4 rb0, rb1;

    auto load_regs = [&](int kt) {
        int k0 = kt * 32;
        #pragma unroll
        for (int s = 0; s < 2; ++s) {
            if (grok) {
                const float* pp = &x[(size_t)gr * DIN + k0 + c0 + s * 8];
                ra[s][0] = *(const float4*)pp;
                ra[s][1] = *(const float4*)(pp + 4);
            } else {
                ra[s][0] = make_float4(0.f, 0.f, 0.f, 0.f);
                ra[s][1] = make_float4(0.f, 0.f, 0.f, 0.f);
            }
        }
        rb0 = *(const uint4*)&W1T[(size_t)bn0 * DIN + k0 + bc0];
        if (hasB1) rb1 = *(const uint4*)&W1T[(size_t)bn1 * DIN + k0 + bc1];
    };
    auto store_lds = [&](int buf) {
        ushort* A = lds + buf * 4096;
        #pragma unroll
        for (int s = 0; s < 2; ++s) {
            int c = c0 + s * 8;
            uint4 wv;
            wv.x = f2bf2(ra[s][0].x, ra[s][0].y);
            wv.y = f2bf2(ra[s][0].z, ra[s][0].w);
            wv.z = f2bf2(ra[s][1].x, ra[s][1].y);
            wv.w = f2bf2(ra[s][1].z, ra[s][1].w);
            *(uint4*)&A[sr * 32 + (c ^ SWZ(sr))] = wv;
        }
        ushort* B = lds + 8192 + buf * 3072;
        *(uint4*)&B[bn0 * 32 + (bc0 ^ SWZ(bn0))] = rb0;
        if (hasB1) *(uint4*)&B[bn1 * 32 + (bc1 ^ SWZ(bn1))] = rb1;
    };

    load_regs(0);
    for (int kt = 0; kt < 16; ++kt) {
        const int buf = kt & 1;
        store_lds(buf);
        __syncthreads();
        if (kt < 15) load_regs(kt + 1);   // issue loads; latency hides under MFMAs
        const int ab = buf * 4096;
        const int bb = buf * 3072;
        s8v b0 = *(s8v*)&lds[bof[0] + bb];
        s8v b1 = *(s8v*)&lds[bof[1] + bb];
        s8v b2 = *(s8v*)&lds[bof[2] + bb];
        #pragma unroll
        for (int i = 0; i < 4; ++i) {
            s8v a = *(s8v*)&lds[aof[i] + ab];
            acc[i][0] = __builtin_amdgcn_mfma_f32_16x16x32_bf16(a, b0, acc[i][0], 0, 0, 0);
            acc[i][1] = __builtin_amdgcn_mfma_f32_16x16x32_bf16(a, b1, acc[i][1], 0, 0, 0);
            acc[i][2] = __builtin_amdgcn_mfma_f32_16x16x32_bf16(a, b2, acc[i][2], 0, 0, 0);
        }
    }

    #pragma unroll
    for (int i = 0; i < 4; ++i) {
        int gr0 = row0 + rb + i * 16 + lq * 4;
        #pragma unroll
        for (int q = 0; q < 4; ++q) {
            int g = gr0 + q;
            if (g < N) {
                float di = dinv[g];
                #pragma unroll
                for (int j = 0; j < 3; ++j)
                    hs1[(size_t)g * DH + cb + j * 16 + lm] = f2bf(acc[i][j][q] * di);
            }
        }
    }
}

// ---------- agg1: wave per node, 48 lanes x uint, 8-deep (R8 form) ----------
__global__ __launch_bounds__(256) void k_agg1(
    const int* __restrict__ row_ptr, const int* __restrict__ adj,
    const float* __restrict__ dinv, const ushort* __restrict__ hs1,
    const float* __restrict__ b1, ushort* __restrict__ h1, int N)
{
    int t = blockIdx.x * 256 + threadIdx.x;
    int node = t >> 6, lane = t & 63;
    if (node >= N) return;
    int c = lane << 1;
    const bool act = (c < DH);

    float a0 = 0.f, a1 = 0.f;
    if (act) {
        uint u = *(const uint*)&hs1[(size_t)node * DH + c];   // self-loop
        a0 = bflo(u); a1 = bfhi(u);
    }
    int e = row_ptr[node], e1 = row_ptr[node + 1];
    for (; e + 7 < e1; e += 8) {
        int s0 = adj[e],     s1 = adj[e + 1], s2 = adj[e + 2], s3 = adj[e + 3];
        int s4 = adj[e + 4], s5 = adj[e + 5], s6 = adj[e + 6], s7 = adj[e + 7];
        if (act) {
            uint u0 = *(const uint*)&hs1[(size_t)s0 * DH + c];
            uint u1 = *(const uint*)&hs1[(size_t)s1 * DH + c];
            uint u2 = *(const uint*)&hs1[(size_t)s2 * DH + c];
            uint u3 = *(const uint*)&hs1[(size_t)s3 * DH + c];
            uint u4 = *(const uint*)&hs1[(size_t)s4 * DH + c];
            uint u5 = *(const uint*)&hs1[(size_t)s5 * DH + c];
            uint u6 = *(const uint*)&hs1[(size_t)s6 * DH + c];
            uint u7 = *(const uint*)&hs1[(size_t)s7 * DH + c];
            a0 += bflo(u0); a1 += bfhi(u0);
            a0 += bflo(u1); a1 += bfhi(u1);
            a0 += bflo(u2); a1 += bfhi(u2);
            a0 += bflo(u3); a1 += bfhi(u3);
            a0 += bflo(u4); a1 += bfhi(u4);
            a0 += bflo(u5); a1 += bfhi(u5);
            a0 += bflo(u6); a1 += bfhi(u6);
            a0 += bflo(u7); a1 += bfhi(u7);
        }
    }
    for (; e < e1; ++e) {
        int s = adj[e];
        if (act) {
            uint u = *(const uint*)&hs1[(size_t)s * DH + c];
            a0 += bflo(u); a1 += bfhi(u);
        }
    }
    if (act) {
        float di = dinv[node];
        float r0 = fmaxf(fmaf(a0, di, b1[c]), 0.f);
        float r1 = fmaxf(fmaf(a1, di, b1[c + 1]), 0.f);
        *(uint*)&h1[(size_t)node * DH + c] = f2bf2(r0, r1);
    }
}

// ---------- GEMM2 (MFMA bf16): hs2b = bf16((h1 @ W2) * dinv), row stride 64 ----------
__global__ __launch_bounds__(256) void k_gemm2(
    const ushort* __restrict__ h1, const ushort* __restrict__ W2T,
    const float* __restrict__ dinv, ushort* __restrict__ hs2b, int N)
{
    __shared__ __align__(16) ushort lds[16384 + 48 * 128];
    const int tid = threadIdx.x;
    const int row0 = blockIdx.x * 128;

    for (int f = tid; f < 576; f += 256) {
        int r = f / 12, c = (f % 12) * 8;
        uint4 v = *(const uint4*)&W2T[r * DH + c];
        *(uint4*)&lds[16384 + r * 128 + (c ^ ((r & 7) << 3))] = v;
    }
    {
        int r = tid >> 1, half = tid & 1;
        int gr = row0 + r;
        #pragma unroll
        for (int i = 0; i < 6; ++i) {
            int c = half * 48 + i * 8;
            uint4 v = make_uint4(0, 0, 0, 0);
            if (gr < N) v = *(const uint4*)&h1[(size_t)gr * DH + c];
            *(uint4*)&lds[r * 128 + (c ^ ((r & 7) << 3))] = v;
        }
    }
    __syncthreads();

    const int lane = tid & 63, w = tid >> 6;
    const int rb = w * 32, lm = lane & 15, lq = lane >> 4;
    f4v acc[2][3];
    #pragma unroll
    for (int i = 0; i < 2; ++i)
        #pragma unroll
        for (int j = 0; j < 3; ++j) acc[i][j] = (f4v)0.f;

    #pragma unroll
    for (int ks = 0; ks < 3; ++ks) {
        int kk = ks * 32 + lq * 8;
        s8v b[3];
        #pragma unroll
        for (int j = 0; j < 3; ++j) {
            int n = j * 16 + lm;
            b[j] = *(s8v*)&lds[16384 + n * 128 + (kk ^ ((n & 7) << 3))];
        }
        #pragma unroll
        for (int i = 0; i < 2; ++i) {
            int r = rb + i * 16 + lm;
            s8v a = *(s8v*)&lds[r * 128 + (kk ^ ((r & 7) << 3))];
            #pragma unroll
            for (int j = 0; j < 3; ++j)
                acc[i][j] = __builtin_amdgcn_mfma_f32_16x16x32_bf16(a, b[j], acc[i][j], 0, 0, 0);
        }
    }

    #pragma unroll
    for (int i = 0; i < 2; ++i) {
        int gr0 = row0 + rb + i * 16 + lq * 4;
        #pragma unroll
        for (int q = 0; q < 4; ++q) {
            int gr = gr0 + q;
            if (gr < N) {
                float di = dinv[gr];
                #pragma unroll
                for (int j = 0; j < 3; ++j) {
                    int col = j * 16 + lm;
                    if (col < DOUT)
                        hs2b[(size_t)gr * 64 + col] = f2bf(acc[i][j][q] * di);
                }
            }
        }
    }
}

// ---------- agg2 + bias + log_softmax: wave per node, 20 lanes x uint (R8 form) ----------
__global__ __launch_bounds__(256) void k_agg2sm(
    const int* __restrict__ row_ptr, const int* __restrict__ adj,
    const float* __restrict__ dinv, const ushort* __restrict__ hs2b,
    const float* __restrict__ b2, float* __restrict__ out,
    float* __restrict__ lsm, int N)
{
    int t = blockIdx.x * 256 + threadIdx.x;
    int node = t >> 6, lane = t & 63;
    if (node >= N) return;
    int c = lane << 1;
    const bool act = (c < DOUT);   // lanes 0..19

    float a0 = 0.f, a1 = 0.f;
    if (act) {
        uint u = *(const uint*)&hs2b[(size_t)node * 64 + c];   // self-loop
        a0 = bflo(u); a1 = bfhi(u);
    }
    int e = row_ptr[node], e1 = row_ptr[node + 1];
    for (; e + 7 < e1; e += 8) {
        int s0 = adj[e],     s1 = adj[e + 1], s2 = adj[e + 2], s3 = adj[e + 3];
        int s4 = adj[e + 4], s5 = adj[e + 5], s6 = adj[e + 6], s7 = adj[e + 7];
        if (act) {
            uint u0 = *(const uint*)&hs2b[(size_t)s0 * 64 + c];
            uint u1 = *(const uint*)&hs2b[(size_t)s1 * 64 + c];
            uint u2 = *(const uint*)&hs2b[(size_t)s2 * 64 + c];
            uint u3 = *(const uint*)&hs2b[(size_t)s3 * 64 + c];
            uint u4 = *(const uint*)&hs2b[(size_t)s4 * 64 + c];
            uint u5 = *(const uint*)&hs2b[(size_t)s5 * 64 + c];
            uint u6 = *(const uint*)&hs2b[(size_t)s6 * 64 + c];
            uint u7 = *(const uint*)&hs2b[(size_t)s7 * 64 + c];
            a0 += bflo(u0); a1 += bfhi(u0);
            a0 += bflo(u1); a1 += bfhi(u1);
            a0 += bflo(u2); a1 += bfhi(u2);
            a0 += bflo(u3); a1 += bfhi(u3);
            a0 += bflo(u4); a1 += bfhi(u4);
            a0 += bflo(u5); a1 += bfhi(u5);
            a0 += bflo(u6); a1 += bfhi(u6);
            a0 += bflo(u7); a1 += bfhi(u7);
        }
    }
    for (; e < e1; ++e) {
        int s = adj[e];
        if (act) {
            uint u = *(const uint*)&hs2b[(size_t)s * 64 + c];
            a0 += bflo(u); a1 += bfhi(u);
        }
    }

    float di = act ? dinv[node] : 0.f;
    float v0 = act ? fmaf(a0, di, b2[c]) : -1e30f;
    float v1 = act ? fmaf(a1, di, b2[c + 1]) : -1e30f;
    float m = fmaxf(v0, v1);
    #pragma unroll
    for (int off = 32; off >= 1; off >>= 1) m = fmaxf(m, __shfl_xor(m, off));
    float ex = act ? (__expf(v0 - m) + __expf(v1 - m)) : 0.f;
    float s = ex;
    #pragma unroll
    for (int off = 32; off >= 1; off >>= 1) s += __shfl_xor(s, off);
    float lse = m + __logf(s);
    if (act) {
        *(float2*)&out[(size_t)node * DOUT + c] = make_float2(v0, v1);
        *(float2*)&lsm[(size_t)node * DOUT + c] = make_float2(v0 - lse, v1 - lse);
    }
}

extern "C" void kernel_launch(void* const* d_in, const int* in_sizes, int n_in,
                              void* d_out, int out_size, void* d_ws, size_t ws_size,
                              hipStream_t stream) {
    const float* x  = (const float*)d_in[0];
    const int*   ei = (const int*)d_in[1];
    const float* W1 = (const float*)d_in[2];
    const float* b1 = (const float*)d_in[3];
    const float* W2 = (const float*)d_in[4];
    const float* b2 = (const float*)d_in[5];

    const int N = in_sizes[0] / DIN;
    const int E = in_sizes[1] / 2;
    const int* srcp = ei;
    const int* dstp = ei + E;
    const int SB = (N + 255) / 256;

    ushort* hs1  = (ushort*)d_ws;                   // N*96 bf16
    ushort* h1   = hs1 + (size_t)N * DH;            // N*96 bf16
    ushort* hs2b = h1 + (size_t)N * DH;             // N*64 bf16 (40 used, 128B rows)
    float* dinv  = (float*)(hs2b + (size_t)N * 64); // N
    ushort* W1T  = (ushort*)(dinv + N);             // 96*512 bf16
    ushort* W2T  = W1T + (size_t)DH * DIN;          // 48*96 bf16
    int* cnt     = (int*)(W2T + 48 * DH);           // N
    int* row_ptr = cnt + N;                         // N+1
    int* adj     = row_ptr + N + 1;                 // E
    int* pos     = adj + E;                         // E

    float* out = (float*)d_out;                     // logits [N*40]
    float* lsm = out + (size_t)N * DOUT;            // log_softmax [N*40]

    const int gE = (E + 255) / 256;

    k_prep<<<SB, 256, 0, stream>>>(W1, W2, cnt, W1T, W2T, N);
    k_hist<<<gE, 256, 0, stream>>>(dstp, cnt, pos, E);
    k_rowptr_all<<<SB, 256, 0, stream>>>(cnt, row_ptr, dinv, N);
    k_fill<<<gE, 256, 0, stream>>>(srcp, dstp, row_ptr, pos, adj, E);

    k_gemm1<<<(N + 127) / 128, 256, 0, stream>>>(x, W1T, dinv, hs1, N);
    k_agg1<<<(int)(((size_t)N * 64 + 255) / 256), 256, 0, stream>>>(row_ptr, adj, dinv, hs1, b1, h1, N);

    k_gemm2<<<(N + 127) / 128, 256, 0, stream>>>(h1, W2T, dinv, hs2b, N);
    k_agg2sm<<<(int)(((size_t)N * 64 + 255) / 256), 256, 0, stream>>>(row_ptr, adj, dinv, hs2b, b2, out, lsm, N);
}

// Round 12
// 181.626 us; speedup vs baseline: 1.1223x; 1.1010x over previous
//
#include <hip/hip_runtime.h>
#include <hip/hip_bf16.h>
#include <cstdint>
#include <cstddef>

#define DIN 512
#define DH  96
#define DOUT 40

typedef __attribute__((ext_vector_type(8))) short s8v;
typedef __attribute__((ext_vector_type(4))) float f4v;

__device__ __forceinline__ ushort f2bf(float f) {
    uint u = __float_as_uint(f);
    u += 0x7fffu + ((u >> 16) & 1u);   // RNE
    return (ushort)(u >> 16);
}
__device__ __forceinline__ uint f2bf2(float lo, float hi) {
    __hip_bfloat162 h = __float22bfloat162_rn(make_float2(lo, hi));  // v_cvt_pk_bf16_f32
    return *(uint*)&h;
}
__device__ __forceinline__ float bflo(uint u) { return __uint_as_float(u << 16); }
__device__ __forceinline__ float bfhi(uint u) { return __uint_as_float(u & 0xffff0000u); }

// ---------- prep: zero cnt + W1T bf16 [96][512] + W2T bf16 [48][96] ----------
__global__ __launch_bounds__(256) void k_prep(
    const float* __restrict__ W1, const float* __restrict__ W2,
    int* __restrict__ cnt, ushort* __restrict__ W1T, ushort* __restrict__ W2T, int N)
{
    int i = blockIdx.x * 256 + threadIdx.x;
    if (i < N) cnt[i] = 0;
    if (i < DIN * DH) {
        int k = i / DH, n = i % DH;
        W1T[(size_t)n * DIN + k] = f2bf(W1[i]);
    }
    if (i < 48 * DH) {
        int n = i / DH, k = i % DH;
        W2T[i] = (n < DOUT) ? f2bf(W2[(size_t)k * DOUT + n]) : (ushort)0;
    }
}

// ---------- hist + per-edge slot ----------
__global__ __launch_bounds__(256) void k_hist(
    const int* __restrict__ dst, int* __restrict__ cnt, int* __restrict__ pos, int E)
{
    int e = blockIdx.x * 256 + threadIdx.x;
    if (e < E) pos[e] = atomicAdd(&cnt[dst[e]], 1);
}

__global__ __launch_bounds__(256) void k_blocksum(const int* __restrict__ cnt, int* __restrict__ bsum, int N) {
    int i = blockIdx.x * 256 + threadIdx.x;
    int c = (i < N) ? cnt[i] : 0;
    #pragma unroll
    for (int off = 32; off >= 1; off >>= 1) c += __shfl_down(c, off, 64);
    __shared__ int wsum[4];
    if ((threadIdx.x & 63) == 0) wsum[threadIdx.x >> 6] = c;
    __syncthreads();
    if (threadIdx.x == 0) bsum[blockIdx.x] = wsum[0] + wsum[1] + wsum[2] + wsum[3];
}

__global__ __launch_bounds__(256) void k_scan_small(const int* __restrict__ bsum, int* __restrict__ boff, int SB) {
    __shared__ int p[256];
    int tid = threadIdx.x;
    int v = (tid < SB) ? bsum[tid] : 0;
    p[tid] = v;
    __syncthreads();
    #pragma unroll
    for (int off = 1; off < 256; off <<= 1) {
        int t = (tid >= off) ? p[tid - off] : 0;
        __syncthreads();
        p[tid] += t;
        __syncthreads();
    }
    if (tid < SB) boff[tid] = p[tid] - v;   // exclusive
}

__global__ __launch_bounds__(256) void k_rowptr(
    const int* __restrict__ cnt, const int* __restrict__ boff,
    int* __restrict__ row_ptr, float* __restrict__ dinv, int N)
{
    __shared__ int p[256];
    int tid = threadIdx.x;
    int i = blockIdx.x * 256 + tid;
    int c = (i < N) ? cnt[i] : 0;
    p[tid] = c;
    __syncthreads();
    #pragma unroll
    for (int off = 1; off < 256; off <<= 1) {
        int t = (tid >= off) ? p[tid - off] : 0;
        __syncthreads();
        p[tid] += t;
        __syncthreads();
    }
    int excl = p[tid] - c;
    if (i < N) {
        int base = boff[blockIdx.x] + excl;
        row_ptr[i] = base;
        dinv[i] = rsqrtf(1.0f + (float)c);
        if (i == N - 1) row_ptr[N] = base + c;
    }
}

// ---------- CSR fill (atomic-free) ----------
__global__ __launch_bounds__(256) void k_fill(
    const int* __restrict__ src, const int* __restrict__ dst,
    const int* __restrict__ row_ptr, const int* __restrict__ pos,
    int* __restrict__ adj, int E)
{
    int e = blockIdx.x * 256 + threadIdx.x;
    if (e >= E) return;
    adj[row_ptr[dst[e]] + pos[e]] = src[e];
}

// ---------- GEMM1 (MFMA bf16, BK=32, 28.7KB LDS) ----------
// hs1 = bf16((x @ W1) * dinv); block tile 128x96, wave tile 64x48
#define SWZ(r) (((r >> 1) & 3) << 3)
__global__ __launch_bounds__(256) void k_gemm1(
    const float* __restrict__ x, const ushort* __restrict__ W1T,
    const float* __restrict__ dinv, ushort* __restrict__ hs1, int N)
{
    __shared__ __align__(16) ushort lds[14336];   // A: 2*4096, B: 2*3072
    const int tid = threadIdx.x;
    const int row0 = blockIdx.x * 128;
    const int lane = tid & 63, w = tid >> 6;
    const int rb = (w >> 1) * 64, cb = (w & 1) * 48;
    const int lm = lane & 15, lq = lane >> 4;

    int aof[4], bof[3];
    #pragma unroll
    for (int i = 0; i < 4; ++i) {
        int r = rb + i * 16 + lm;
        aof[i] = r * 32 + ((lq * 8) ^ SWZ(r));
    }
    #pragma unroll
    for (int j = 0; j < 3; ++j) {
        int n = cb + j * 16 + lm;
        bof[j] = 8192 + n * 32 + ((lq * 8) ^ SWZ(n));
    }

    f4v acc[4][3];
    #pragma unroll
    for (int i = 0; i < 4; ++i)
        #pragma unroll
        for (int j = 0; j < 3; ++j) acc[i][j] = (f4v)0.f;

    const int sr = tid >> 1;            // staging row
    const int c0 = (tid & 1) * 16;      // staging col base (16 cols per thread)

    auto stage = [&](int kt, int buf) {
        int k0 = kt * 32;
        int gr = row0 + sr;
        ushort* A = lds + buf * 4096;
        #pragma unroll
        for (int s = 0; s < 2; ++s) {
            int c = c0 + s * 8;
            float4 v0 = make_float4(0.f, 0.f, 0.f, 0.f), v1 = v0;
            if (gr < N) {
                const float* pp = &x[(size_t)gr * DIN + k0 + c];
                v0 = *(const float4*)pp;
                v1 = *(const float4*)(pp + 4);
            }
            uint4 wv;
            wv.x = f2bf2(v0.x, v0.y);
            wv.y = f2bf2(v0.z, v0.w);
            wv.z = f2bf2(v1.x, v1.y);
            wv.w = f2bf2(v1.z, v1.w);
            *(uint4*)&A[sr * 32 + (c ^ SWZ(sr))] = wv;
        }
        ushort* B = lds + 8192 + buf * 3072;
        #pragma unroll
        for (int f = tid; f < 384; f += 256) {
            int n = f >> 2, cc = (f & 3) * 8;
            uint4 wv = *(const uint4*)&W1T[(size_t)n * DIN + k0 + cc];
            *(uint4*)&B[n * 32 + (cc ^ SWZ(n))] = wv;
        }
    };

    stage(0, 0);
    for (int kt = 0; kt < 16; ++kt) {
        __syncthreads();
        if (kt < 15) stage(kt + 1, (kt + 1) & 1);
        const int ab = (kt & 1) * 4096;
        const int bb = (kt & 1) * 3072;
        s8v b0 = *(s8v*)&lds[bof[0] + bb];
        s8v b1 = *(s8v*)&lds[bof[1] + bb];
        s8v b2 = *(s8v*)&lds[bof[2] + bb];
        #pragma unroll
        for (int i = 0; i < 4; ++i) {
            s8v a = *(s8v*)&lds[aof[i] + ab];
            acc[i][0] = __builtin_amdgcn_mfma_f32_16x16x32_bf16(a, b0, acc[i][0], 0, 0, 0);
            acc[i][1] = __builtin_amdgcn_mfma_f32_16x16x32_bf16(a, b1, acc[i][1], 0, 0, 0);
            acc[i][2] = __builtin_amdgcn_mfma_f32_16x16x32_bf16(a, b2, acc[i][2], 0, 0, 0);
        }
    }

    #pragma unroll
    for (int i = 0; i < 4; ++i) {
        int gr0 = row0 + rb + i * 16 + lq * 4;
        #pragma unroll
        for (int q = 0; q < 4; ++q) {
            int gr = gr0 + q;
            if (gr < N) {
                float di = dinv[gr];
                #pragma unroll
                for (int j = 0; j < 3; ++j)
                    hs1[(size_t)gr * DH + cb + j * 16 + lm] = f2bf(acc[i][j][q] * di);
            }
        }
    }
}

// ---------- agg1: wave per node, 8-deep gather ----------
__global__ __launch_bounds__(256) void k_agg1(
    const int* __restrict__ row_ptr, const int* __restrict__ adj,
    const float* __restrict__ dinv, const ushort* __restrict__ hs1,
    const float* __restrict__ b1, ushort* __restrict__ h1, int N)
{
    int t = blockIdx.x * 256 + threadIdx.x;
    int node = t >> 6, lane = t & 63;
    if (node >= N) return;
    int c = lane << 1;
    const bool act = (c < DH);

    float a0 = 0.f, a1 = 0.f;
    if (act) {
        uint u = *(const uint*)&hs1[(size_t)node * DH + c];   // self-loop
        a0 = bflo(u); a1 = bfhi(u);
    }
    int e = row_ptr[node], e1 = row_ptr[node + 1];
    for (; e + 7 < e1; e += 8) {
        int s0 = adj[e],     s1 = adj[e + 1], s2 = adj[e + 2], s3 = adj[e + 3];
        int s4 = adj[e + 4], s5 = adj[e + 5], s6 = adj[e + 6], s7 = adj[e + 7];
        if (act) {
            uint u0 = *(const uint*)&hs1[(size_t)s0 * DH + c];
            uint u1 = *(const uint*)&hs1[(size_t)s1 * DH + c];
            uint u2 = *(const uint*)&hs1[(size_t)s2 * DH + c];
            uint u3 = *(const uint*)&hs1[(size_t)s3 * DH + c];
            uint u4 = *(const uint*)&hs1[(size_t)s4 * DH + c];
            uint u5 = *(const uint*)&hs1[(size_t)s5 * DH + c];
            uint u6 = *(const uint*)&hs1[(size_t)s6 * DH + c];
            uint u7 = *(const uint*)&hs1[(size_t)s7 * DH + c];
            a0 += bflo(u0); a1 += bfhi(u0);
            a0 += bflo(u1); a1 += bfhi(u1);
            a0 += bflo(u2); a1 += bfhi(u2);
            a0 += bflo(u3); a1 += bfhi(u3);
            a0 += bflo(u4); a1 += bfhi(u4);
            a0 += bflo(u5); a1 += bfhi(u5);
            a0 += bflo(u6); a1 += bfhi(u6);
            a0 += bflo(u7); a1 += bfhi(u7);
        }
    }
    for (; e < e1; ++e) {
        int s = adj[e];
        if (act) {
            uint u = *(const uint*)&hs1[(size_t)s * DH + c];
            a0 += bflo(u); a1 += bfhi(u);
        }
    }
    if (act) {
        float di = dinv[node];
        float r0 = fmaxf(fmaf(a0, di, b1[c]), 0.f);
        float r1 = fmaxf(fmaf(a1, di, b1[c + 1]), 0.f);
        *(uint*)&h1[(size_t)node * DH + c] = f2bf2(r0, r1);
    }
}

// ---------- GEMM2 (MFMA bf16): hs2b = bf16((h1 @ W2) * dinv), row stride 64 (128B lines) ----------
__global__ __launch_bounds__(256) void k_gemm2(
    const ushort* __restrict__ h1, const ushort* __restrict__ W2T,
    const float* __restrict__ dinv, ushort* __restrict__ hs2b, int N)
{
    __shared__ __align__(16) ushort lds[16384 + 48 * 128];
    const int tid = threadIdx.x;
    const int row0 = blockIdx.x * 128;

    for (int f = tid; f < 576; f += 256) {
        int r = f / 12, c = (f % 12) * 8;
        uint4 v = *(const uint4*)&W2T[r * DH + c];
        *(uint4*)&lds[16384 + r * 128 + (c ^ ((r & 7) << 3))] = v;
    }
    {
        int r = tid >> 1, half = tid & 1;
        int gr = row0 + r;
        #pragma unroll
        for (int i = 0; i < 6; ++i) {
            int c = half * 48 + i * 8;
            uint4 v = make_uint4(0, 0, 0, 0);
            if (gr < N) v = *(const uint4*)&h1[(size_t)gr * DH + c];
            *(uint4*)&lds[r * 128 + (c ^ ((r & 7) << 3))] = v;
        }
    }
    __syncthreads();

    const int lane = tid & 63, w = tid >> 6;
    const int rb = w * 32, lm = lane & 15, lq = lane >> 4;
    f4v acc[2][3];
    #pragma unroll
    for (int i = 0; i < 2; ++i)
        #pragma unroll
        for (int j = 0; j < 3; ++j) acc[i][j] = (f4v)0.f;

    #pragma unroll
    for (int ks = 0; ks < 3; ++ks) {
        int kk = ks * 32 + lq * 8;
        s8v b[3];
        #pragma unroll
        for (int j = 0; j < 3; ++j) {
            int n = j * 16 + lm;
            b[j] = *(s8v*)&lds[16384 + n * 128 + (kk ^ ((n & 7) << 3))];
        }
        #pragma unroll
        for (int i = 0; i < 2; ++i) {
            int r = rb + i * 16 + lm;
            s8v a = *(s8v*)&lds[r * 128 + (kk ^ ((r & 7) << 3))];
            #pragma unroll
            for (int j = 0; j < 3; ++j)
                acc[i][j] = __builtin_amdgcn_mfma_f32_16x16x32_bf16(a, b[j], acc[i][j], 0, 0, 0);
        }
    }

    #pragma unroll
    for (int i = 0; i < 2; ++i) {
        int gr0 = row0 + rb + i * 16 + lq * 4;
        #pragma unroll
        for (int q = 0; q < 4; ++q) {
            int gr = gr0 + q;
            if (gr < N) {
                float di = dinv[gr];
                #pragma unroll
                for (int j = 0; j < 3; ++j) {
                    int col = j * 16 + lm;
                    if (col < DOUT)
                        hs2b[(size_t)gr * 64 + col] = f2bf(acc[i][j][q] * di);
                }
            }
        }
    }
}

// ---------- agg2 + bias + log_softmax fused: wave/node, 1 cache line per edge ----------
__global__ __launch_bounds__(256) void k_agg2sm(
    const int* __restrict__ row_ptr, const int* __restrict__ adj,
    const float* __restrict__ dinv, const ushort* __restrict__ hs2b,
    const float* __restrict__ b2, float* __restrict__ out,
    float* __restrict__ lsm, int N)
{
    int t = blockIdx.x * 256 + threadIdx.x;
    int node = t >> 6, lane = t & 63;
    if (node >= N) return;
    int c = lane << 1;
    const bool act = (c < DOUT);   // lanes 0..19

    float a0 = 0.f, a1 = 0.f;
    if (act) {
        uint u = *(const uint*)&hs2b[(size_t)node * 64 + c];   // self-loop
        a0 = bflo(u); a1 = bfhi(u);
    }
    int e = row_ptr[node], e1 = row_ptr[node + 1];
    for (; e + 7 < e1; e += 8) {
        int s0 = adj[e],     s1 = adj[e + 1], s2 = adj[e + 2], s3 = adj[e + 3];
        int s4 = adj[e + 4], s5 = adj[e + 5], s6 = adj[e + 6], s7 = adj[e + 7];
        if (act) {
            uint u0 = *(const uint*)&hs2b[(size_t)s0 * 64 + c];
            uint u1 = *(const uint*)&hs2b[(size_t)s1 * 64 + c];
            uint u2 = *(const uint*)&hs2b[(size_t)s2 * 64 + c];
            uint u3 = *(const uint*)&hs2b[(size_t)s3 * 64 + c];
            uint u4 = *(const uint*)&hs2b[(size_t)s4 * 64 + c];
            uint u5 = *(const uint*)&hs2b[(size_t)s5 * 64 + c];
            uint u6 = *(const uint*)&hs2b[(size_t)s6 * 64 + c];
            uint u7 = *(const uint*)&hs2b[(size_t)s7 * 64 + c];
            a0 += bflo(u0); a1 += bfhi(u0);
            a0 += bflo(u1); a1 += bfhi(u1);
            a0 += bflo(u2); a1 += bfhi(u2);
            a0 += bflo(u3); a1 += bfhi(u3);
            a0 += bflo(u4); a1 += bfhi(u4);
            a0 += bflo(u5); a1 += bfhi(u5);
            a0 += bflo(u6); a1 += bfhi(u6);
            a0 += bflo(u7); a1 += bfhi(u7);
        }
    }
    for (; e < e1; ++e) {
        int s = adj[e];
        if (act) {
            uint u = *(const uint*)&hs2b[(size_t)s * 64 + c];
            a0 += bflo(u); a1 += bfhi(u);
        }
    }

    float di = act ? dinv[node] : 0.f;
    float v0 = act ? fmaf(a0, di, b2[c]) : -1e30f;
    float v1 = act ? fmaf(a1, di, b2[c + 1]) : -1e30f;
    float m = fmaxf(v0, v1);
    #pragma unroll
    for (int off = 32; off >= 1; off >>= 1) m = fmaxf(m, __shfl_xor(m, off));
    float ex = act ? (__expf(v0 - m) + __expf(v1 - m)) : 0.f;
    float s = ex;
    #pragma unroll
    for (int off = 32; off >= 1; off >>= 1) s += __shfl_xor(s, off);
    float lse = m + __logf(s);
    if (act) {
        *(float2*)&out[(size_t)node * DOUT + c] = make_float2(v0, v1);
        *(float2*)&lsm[(size_t)node * DOUT + c] = make_float2(v0 - lse, v1 - lse);
    }
}

extern "C" void kernel_launch(void* const* d_in, const int* in_sizes, int n_in,
                              void* d_out, int out_size, void* d_ws, size_t ws_size,
                              hipStream_t stream) {
    const float* x  = (const float*)d_in[0];
    const int*   ei = (const int*)d_in[1];
    const float* W1 = (const float*)d_in[2];
    const float* b1 = (const float*)d_in[3];
    const float* W2 = (const float*)d_in[4];
    const float* b2 = (const float*)d_in[5];

    const int N = in_sizes[0] / DIN;
    const int E = in_sizes[1] / 2;
    const int* srcp = ei;
    const int* dstp = ei + E;
    const int SB = (N + 255) / 256;

    ushort* hs1  = (ushort*)d_ws;                   // N*96 bf16
    ushort* h1   = hs1 + (size_t)N * DH;            // N*96 bf16
    ushort* hs2b = h1 + (size_t)N * DH;             // N*64 bf16 (40 used, 128B rows)
    float* dinv  = (float*)(hs2b + (size_t)N * 64); // N
    ushort* W1T  = (ushort*)(dinv + N);             // 96*512 bf16
    ushort* W2T  = W1T + (size_t)DH * DIN;          // 48*96 bf16
    int* cnt     = (int*)(W2T + 48 * DH);           // N
    int* row_ptr = cnt + N;                         // N+1
    int* adj     = row_ptr + N + 1;                 // E
    int* pos     = adj + E;                         // E
    int* bsum    = pos + E;                         // SB
    int* boff    = bsum + SB;                       // SB

    float* out = (float*)d_out;                     // logits [N*40]
    float* lsm = out + (size_t)N * DOUT;            // log_softmax [N*40]

    const int gE = (E + 255) / 256;

    k_prep<<<SB, 256, 0, stream>>>(W1, W2, cnt, W1T, W2T, N);
    k_hist<<<gE, 256, 0, stream>>>(dstp, cnt, pos, E);
    k_blocksum<<<SB, 256, 0, stream>>>(cnt, bsum, N);
    k_scan_small<<<1, 256, 0, stream>>>(bsum, boff, SB);
    k_rowptr<<<SB, 256, 0, stream>>>(cnt, boff, row_ptr, dinv, N);
    k_fill<<<gE, 256, 0, stream>>>(srcp, dstp, row_ptr, pos, adj, E);

    k_gemm1<<<(N + 127) / 128, 256, 0, stream>>>(x, W1T, dinv, hs1, N);
    k_agg1<<<(int)(((size_t)N * 64 + 255) / 256), 256, 0, stream>>>(row_ptr, adj, dinv, hs1, b1, h1, N);

    k_gemm2<<<(N + 127) / 128, 256, 0, stream>>>(h1, W2T, dinv, hs2b, N);
    k_agg2sm<<<(int)(((size_t)N * 64 + 255) / 256), 256, 0, stream>>>(row_ptr, adj, dinv, hs2b, b2, out, lsm, N);
}